// Round 5
// baseline (70.125 us; speedup 1.0000x reference)
//
#include <hip/hip_runtime.h>

typedef __attribute__((ext_vector_type(8))) short bf16x8;
typedef __attribute__((ext_vector_type(4))) float f32x4;

#define GAMMA_ 0.5f
#define LOG2E_ 1.4426950408889634f

constexpr int D  = 256;   // feature dim (K)
constexpr int BM = 256;   // rows of X per block
constexpr int BN = 256;   // X_train rows per block
constexpr int NT = 4;     // K-steps of 64
constexpr int HT = 16384; // half-tile bytes: 128 rows x 128 B

// ---------- helpers ----------
__device__ __forceinline__ unsigned short f2bf(float f) {
    unsigned int x = __float_as_uint(f);
    x += 0x7FFFu + ((x >> 16) & 1u);          // RNE
    return (unsigned short)(x >> 16);
}

__device__ __forceinline__ void gload16(void* lds, const void* g) {
    __builtin_amdgcn_global_load_lds(
        (const __attribute__((address_space(1))) void*)g,
        (__attribute__((address_space(3))) void*)lds, 16, 0, 0);
}

// ---------- prep: cast to bf16, row |x|^2, coefs, out-init ----------
__global__ void prep_all_kernel(const float* __restrict__ X,
                                const float* __restrict__ Xt,
                                const float* __restrict__ alphas,
                                const float* __restrict__ y,
                                const float* __restrict__ b,
                                unsigned short* __restrict__ Abf,
                                unsigned short* __restrict__ Bbf,
                                float* __restrict__ srow,
                                float* __restrict__ tcol,
                                float* __restrict__ coef,
                                float* __restrict__ out,
                                int N, int M) {
    int w = threadIdx.x >> 6;         // one wave per row
    int l = threadIdx.x & 63;
    int row = blockIdx.x * 4 + w;
    if (row >= N + M) return;
    const float* src;
    unsigned short* dst;
    if (row < N) { src = X  + (size_t)row * D;       dst = Abf + (size_t)row * D; }
    else         { src = Xt + (size_t)(row - N) * D; dst = Bbf + (size_t)(row - N) * D; }
    const float4 v = reinterpret_cast<const float4*>(src)[l];
    ushort4 u;
    u.x = f2bf(v.x); u.y = f2bf(v.y); u.z = f2bf(v.z); u.w = f2bf(v.w);
    reinterpret_cast<ushort4*>(dst)[l] = u;
    float ss = v.x * v.x + v.y * v.y + v.z * v.z + v.w * v.w;
    #pragma unroll
    for (int off = 32; off >= 1; off >>= 1) ss += __shfl_xor(ss, off);
    if (l == 0) {
        float folded = -GAMMA_ * LOG2E_ * ss;
        if (row < N) { srow[row] = folded; out[row] = b[0]; }
        else {
            int r2 = row - N;
            tcol[r2] = folded;
            coef[r2] = alphas[r2] * y[r2];
        }
    }
}

// ---------- fused RBF-SVM predict, 8-phase 256x256 schedule ----------
// pred_i = sum_j exp2( s_i + t_j + (2*g*log2e) * <x_i, xt_j> ) * coef_j + b
__launch_bounds__(512, 2)
__global__ void svm_main_kernel(const unsigned short* __restrict__ Abf,
                                const unsigned short* __restrict__ Bbf,
                                const float* __restrict__ srow,
                                const float* __restrict__ tcol,
                                const float* __restrict__ coef,
                                float* __restrict__ out) {
    __shared__ char L[131072];   // A: [0,64K)  B: [64K,128K); each 2buf x 2half x 16K

    const int tid = threadIdx.x;
    const int w   = tid >> 6;          // wave 0..7
    const int l   = tid & 63;
    const int wr  = w >> 2;            // 2x4 wave grid; wave tile 128x64
    const int wcn = w & 3;
    const int hi  = l >> 4;
    const int lo  = l & 15;
    const int row0 = blockIdx.x * BM;
    const int col0 = blockIdx.y * BN;

    const char* Ag = (const char*)Abf + (size_t)row0 * 512;
    const char* Bg = (const char*)Bbf + (size_t)col0 * 512;

// stage half-tile H of K-step T into buffer BUF (linear LDS dest,
// inverse-swizzled global source; involution byte ^= (row&7)<<4)
#define ISSUE(gbase, OPOFF, T, H, BUF)                                         \
    {                                                                          \
        _Pragma("unroll")                                                      \
        for (int c = 0; c < 2; ++c) {                                          \
            int x = c * 8192 + tid * 16;                                       \
            int r = x >> 7;                                                    \
            int s = ((H) * 128 + r) * 512 + (T) * 128                          \
                  + ((x & 127) ^ ((r & 7) << 4));                              \
            gload16(L + (OPOFF) + ((BUF) * 2 + (H)) * HT + c * 8192 + w * 1024,\
                    (gbase) + s);                                              \
        }                                                                      \
    }

    f32x4 acc[8][4];
    #pragma unroll
    for (int i = 0; i < 8; ++i)
        #pragma unroll
        for (int j = 0; j < 4; ++j) { f32x4 z = {0.f,0.f,0.f,0.f}; acc[i][j] = z; }

    bf16x8 afr[4][2];      // current row-half's A frags
    bf16x8 bfr[2][2][2];   // [nh][ni2][ks]

#define LOADA(B, MH)                                                           \
    {                                                                          \
        _Pragma("unroll")                                                      \
        for (int mi2 = 0; mi2 < 4; ++mi2) {                                    \
            int ra = ((MH) * 4 + mi2) * 16 + lo;                               \
            _Pragma("unroll")                                                  \
            for (int ks = 0; ks < 2; ++ks) {                                   \
                int off = ((B) * 2 + wr) * HT + ra * 128                       \
                        + ((ks * 64 + hi * 16) ^ ((ra & 7) << 4));             \
                afr[mi2][ks] = *(const bf16x8*)(L + off);                      \
            }                                                                  \
        }                                                                      \
    }

#define LOADB(B, NH)                                                           \
    {                                                                          \
        _Pragma("unroll")                                                      \
        for (int ni2 = 0; ni2 < 2; ++ni2) {                                    \
            int cb = wcn * 64 + ((NH) * 2 + ni2) * 16 + lo;                    \
            int hb = cb >> 7;                                                  \
            int rb = cb & 127;                                                 \
            _Pragma("unroll")                                                  \
            for (int ks = 0; ks < 2; ++ks) {                                   \
                int off = 65536 + ((B) * 2 + hb) * HT + rb * 128               \
                        + ((ks * 64 + hi * 16) ^ ((rb & 7) << 4));             \
                bfr[NH][ni2][ks] = *(const bf16x8*)(L + off);                  \
            }                                                                  \
        }                                                                      \
    }

#define MMA(MH, NH)                                                            \
    {                                                                          \
        __builtin_amdgcn_s_setprio(1);                                         \
        _Pragma("unroll")                                                      \
        for (int ks = 0; ks < 2; ++ks)                                         \
            _Pragma("unroll")                                                  \
            for (int mi2 = 0; mi2 < 4; ++mi2)                                  \
                _Pragma("unroll")                                              \
                for (int ni2 = 0; ni2 < 2; ++ni2)                              \
                    acc[(MH)*4+mi2][(NH)*2+ni2] =                              \
                        __builtin_amdgcn_mfma_f32_16x16x32_bf16(               \
                            afr[mi2][ks], bfr[NH][ni2][ks],                    \
                            acc[(MH)*4+mi2][(NH)*2+ni2], 0, 0, 0);             \
        __builtin_amdgcn_s_setprio(0);                                         \
    }

    // prologue: stage K-step 0 (8 gloads outstanding)
    ISSUE(Ag, 0,     0, 0, 0);
    ISSUE(Ag, 0,     0, 1, 0);
    ISSUE(Bg, 65536, 0, 0, 0);
    ISSUE(Bg, 65536, 0, 1, 0);

    #pragma unroll
    for (int t = 0; t < NT; ++t) {
        const int b  = t & 1;
        const int nb = b ^ 1;
        // ---- P0: wait step-t staging (counted), compute quadrant (0,0) ----
        if (t + 1 < NT) {
            ISSUE(Ag, 0, t + 1, 0, nb);
            asm volatile("s_waitcnt vmcnt(2)" ::: "memory");
        } else {
            asm volatile("s_waitcnt vmcnt(0)" ::: "memory");
        }
        __builtin_amdgcn_s_barrier();
        LOADA(b, 0);
        LOADB(b, 0);
        MMA(0, 0);
        __builtin_amdgcn_s_barrier();
        // ---- P1: quadrant (0,1) ----
        LOADB(b, 1);
        if (t + 1 < NT) ISSUE(Ag, 0, t + 1, 1, nb);
        __builtin_amdgcn_s_barrier();
        MMA(0, 1);
        __builtin_amdgcn_s_barrier();
        // ---- P2: quadrant (1,0) ----
        LOADA(b, 1);
        if (t + 1 < NT) ISSUE(Bg, 65536, t + 1, 0, nb);
        __builtin_amdgcn_s_barrier();
        MMA(1, 0);
        __builtin_amdgcn_s_barrier();
        // ---- P3: quadrant (1,1) ----
        if (t + 1 < NT) ISSUE(Bg, 65536, t + 1, 1, nb);
        __builtin_amdgcn_s_barrier();
        MMA(1, 1);
        __builtin_amdgcn_s_barrier();
    }

    // ---- epilogue (once per block): exp2 + weighted row-accumulate ----
    const float K2G = 2.0f * GAMMA_ * LOG2E_;
    float sreg[8][4];
    #pragma unroll
    for (int mi = 0; mi < 8; ++mi)
        #pragma unroll
        for (int r = 0; r < 4; ++r)
            sreg[mi][r] = srow[row0 + wr * 128 + mi * 16 + hi * 4 + r];

    float partial[8][4];
    #pragma unroll
    for (int mi = 0; mi < 8; ++mi)
        #pragma unroll
        for (int r = 0; r < 4; ++r) partial[mi][r] = 0.0f;

    #pragma unroll
    for (int ni = 0; ni < 4; ++ni) {
        int colg = col0 + wcn * 64 + ni * 16 + lo;
        float tv = tcol[colg];
        float cf = coef[colg];
        #pragma unroll
        for (int mi = 0; mi < 8; ++mi) {
            #pragma unroll
            for (int r = 0; r < 4; ++r) {
                float arg = fmaf(acc[mi][ni][r], K2G, sreg[mi][r] + tv);
                float p = __builtin_amdgcn_exp2f(arg);
                partial[mi][r] = fmaf(p, cf, partial[mi][r]);
            }
        }
    }

    // reduce across the 16 lanes of each row group, one atomicAdd per row
    #pragma unroll
    for (int mi = 0; mi < 8; ++mi) {
        #pragma unroll
        for (int r = 0; r < 4; ++r) {
            float v = partial[mi][r];
            v += __shfl_xor(v, 1);
            v += __shfl_xor(v, 2);
            v += __shfl_xor(v, 4);
            v += __shfl_xor(v, 8);
            if (lo == 0) {
                int rowg = row0 + wr * 128 + mi * 16 + hi * 4 + r;
                atomicAdd(&out[rowg], v);
            }
        }
    }
#undef ISSUE
#undef LOADA
#undef LOADB
#undef MMA
}

// ---------- launcher ----------
extern "C" void kernel_launch(void* const* d_in, const int* in_sizes, int n_in,
                              void* d_out, int out_size, void* d_ws, size_t ws_size,
                              hipStream_t stream) {
    const float* X      = (const float*)d_in[0];
    const float* Xt     = (const float*)d_in[1];
    const float* alphas = (const float*)d_in[2];
    const float* y      = (const float*)d_in[3];
    const float* b      = (const float*)d_in[4];
    float* out = (float*)d_out;

    const int N = in_sizes[0] / D;   // 8192
    const int M = in_sizes[1] / D;   // 8192

    // workspace: bf16 X | bf16 Xt | srow[N] | tcol[M] | coef[M]
    char* ws = (char*)d_ws;
    unsigned short* Abf = (unsigned short*)ws;
    unsigned short* Bbf = Abf + (size_t)N * D;
    float* srow = (float*)(Bbf + (size_t)M * D);
    float* tcol = srow + N;
    float* coef = tcol + M;

    prep_all_kernel<<<(N + M) / 4, 256, 0, stream>>>(X, Xt, alphas, y, b,
                                                     Abf, Bbf, srow, tcol, coef,
                                                     out, N, M);

    dim3 grid(N / BM, M / BN);
    svm_main_kernel<<<grid, 512, 0, stream>>>(Abf, Bbf, srow, tcol, coef, out);
}